// Round 11
// baseline (476.266 us; speedup 1.0000x reference)
//
#include <hip/hip_runtime.h>

#define NTOK   2048
#define DIM    512
#define FDIM   2048
#define NEXP   16
#define CAP    768     // max routed tokens buffered per expert (mean ~256)
#define BT2    128     // token block per P2 tb iteration
#define CNTS   32      // counts stride in ints (128 B -> one L2 line per counter)
#define NBLK   512     // grid: 256 CUs x 2 blocks guaranteed co-resident

typedef __bf16 bf16x8 __attribute__((ext_vector_type(8)));
typedef float  floatx4 __attribute__((ext_vector_type(4)));

// workspace layout (bytes)
#define WS_COUNTS    0         // 16 counters x 128 B apart (memset 0)
#define WS_BAR       64        // barrier counter (memset 0; hole between counters)
#define WS_ZEROPAGE  2048      // 1KB zeros for pad-lane loads (memset 0)
#define WS_TOPIDX    4096      // NTOK*2 ints
#define WS_ROUTW     20480     // NTOK*2 floats
#define WS_HMEAN     36864     // NEXP*FDIM floats (plain-stored by P2 — no zeroing)
#define WS_YMEAN     167936    // NEXP*DIM floats
#define WS_XG        200704    // NEXP*CAP*DIM bf16 = 12.6 MB
#define WS_ZERO_BYTES 3072     // counts + bar + zero page

// Software grid barrier: monotonic counter, release/acquire fences.
// All NBLK blocks are co-resident (launch_bounds(256,2) => >=2 blocks/CU,
// 256 CUs x 2 = 512 = NBLK), so the spin cannot deadlock.
__device__ __forceinline__ void grid_bar(int* bar, int target) {
    __syncthreads();                      // all block threads done; stores drained
    if (threadIdx.x == 0) {
        __threadfence();                  // device-scope release (L2 writeback)
        __hip_atomic_fetch_add(bar, 1, __ATOMIC_RELEASE, __HIP_MEMORY_SCOPE_AGENT);
        while (__hip_atomic_load(bar, __ATOMIC_ACQUIRE, __HIP_MEMORY_SCOPE_AGENT) < target)
            __builtin_amdgcn_s_sleep(2);
    }
    __syncthreads();
    __threadfence();                      // device-scope acquire for all threads
}

// ---------------------------------------------------------------------------
// Single fused kernel (normal launch, no cooperative API):
//   P1 route+gather (4 tok/block) | P2 expert FFN (1 block per (e,f-tile),
//   tb-loop, plain-store hmean) | P3 ymean (16 d/block) | P4 combine.
// grid = 512 x 256, LDS 25.6 KB, __launch_bounds__(256,2) (VGPR<=128).
// ---------------------------------------------------------------------------
__global__ __launch_bounds__(256, 2) void fused_moe(
    const float* __restrict__ x, const float* __restrict__ gw,
    const float* __restrict__ w1, const float* __restrict__ w2,
    int* counts, int* bar, int* top_idx, float* routw, __bf16* Xg,
    const __bf16* zp, float* hmean, float* ymean, float* out)
{
    __shared__ __align__(16) char smem[25600];
    const int tid = threadIdx.x;
    const int bid = blockIdx.x;

    // ---------------- P1: gate logits, top-2, gather (4 tokens/block) -------
    {
        float* xt        = (float*)smem;                        // 8192 B
        float (*lg)[17]  = (float(*)[17])(smem + 8192);         // 272 B
        int*   cnt_loc   = (int*)(smem + 8464);
        int*   base_loc  = (int*)(smem + 8528);
        int   (*ei)[2]   = (int(*)[2])(smem + 8592);
        int   (*rk)[2]   = (int(*)[2])(smem + 8624);
        int   (*gdst)[2] = (int(*)[2])(smem + 8656);
        const int t0 = bid * 4;

        if (tid < 16) cnt_loc[tid] = 0;
        {   // stage 4 token rows, coalesced float4
            const float4* src = (const float4*)(x + (size_t)t0 * DIM);
            float4* dst = (float4*)xt;
            #pragma unroll
            for (int i = 0; i < 2; ++i) dst[i * 256 + tid] = src[i * 256 + tid];
        }
        __syncthreads();

        if (tid < 64) {   // logits: thread = (token tl, expert e)
            const int tl = tid >> 4, e = tid & 15;
            const float4* xr = (const float4*)(xt + tl * DIM);
            const float4* gr = (const float4*)(gw + e * DIM);
            float acc = 0.f;
            #pragma unroll 8
            for (int j = 0; j < DIM / 4; ++j) {
                float4 a = xr[j], b = gr[j];
                acc += a.x * b.x + a.y * b.y + a.z * b.z + a.w * b.w;
            }
            lg[tl][e] = acc;
        }
        __syncthreads();

        if (tid < 4) {   // per-token top-2 + softmax + LOCAL rank
            const int tl = tid;
            float v0 = -1e30f, v1 = -1e30f; int i0 = 0, i1 = 0;
            #pragma unroll
            for (int e = 0; e < NEXP; ++e) {
                float v = lg[tl][e];
                if (v > v0)      { v1 = v0; i1 = i0; v0 = v; i0 = e; }
                else if (v > v1) { v1 = v;  i1 = e; }
            }
            float e1 = __expf(v1 - v0);          // v0 >= v1
            float w0 = 1.f / (1.f + e1);
            float w1v = 1.f - w0;
            const int t = t0 + tl;
            top_idx[t * 2]     = i0; top_idx[t * 2 + 1] = i1;
            routw[t * 2]       = w0; routw[t * 2 + 1]   = w1v;
            ei[tl][0] = i0; ei[tl][1] = i1;
            rk[tl][0] = atomicAdd(&cnt_loc[i0], 1);
            rk[tl][1] = atomicAdd(&cnt_loc[i1], 1);
        }
        __syncthreads();
        if (tid < 16) {  // ONE padded global atomic per (block, expert)
            int n = cnt_loc[tid];
            base_loc[tid] = (n > 0) ? atomicAdd(counts + tid * CNTS, n) : 0;
        }
        __syncthreads();
        if (tid < 4) {   // final slot = global base + local rank
            #pragma unroll
            for (int k = 0; k < 2; ++k) {
                int p = base_loc[ei[tid][k]] + rk[tid][k];
                gdst[tid][k] = (p < CAP) ? (ei[tid][k] * CAP + p) : -1;
            }
        }
        __syncthreads();

        // gather-write 8 rows (4 tokens x 2 experts) as bf16, 16B stores
        #pragma unroll
        for (int it = 0; it < 2; ++it) {
            int s   = it * 256 + tid;          // 0..511
            int job = s >> 6, el = s & 63;     // job: (token,k), el: 16B chunk
            int tl  = job >> 1, k = job & 1;
            int dst = gdst[tl][k];
            if (dst >= 0) {
                float4 a = ((const float4*)(xt + tl * DIM))[el * 2];
                float4 b = ((const float4*)(xt + tl * DIM))[el * 2 + 1];
                bf16x8 o;
                o[0] = (__bf16)a.x; o[1] = (__bf16)a.y; o[2] = (__bf16)a.z; o[3] = (__bf16)a.w;
                o[4] = (__bf16)b.x; o[5] = (__bf16)b.y; o[6] = (__bf16)b.z; o[7] = (__bf16)b.w;
                *(bf16x8*)(Xg + (size_t)dst * DIM + el * 8) = o;
            }
        }
    }
    grid_bar(bar, NBLK);

    // ---------------- P2: expert FFN (1 block per (e, 64-f-tile)) -----------
    {
        __bf16* w1s = (__bf16*)smem;                     //  8320 B [kg][f+pad][8]
        __bf16* xs  = (__bf16*)(smem + 8320);            // 16512 B [kg][t+pad][8]
        float (*hred)[2] = (float(*)[2])(smem + 24832);  //   512 B

        const int e   = bid & 15;            // expert fast
        const int f0  = (bid >> 4) * 64;
        const int cnt = min(counts[e * CNTS], CAP);
        const float inv = 1.f / (float)max(cnt, 1);

        const int wv   = tid >> 6;
        const int lane = tid & 63;
        const int q    = lane >> 4;
        const int l15  = lane & 15;
        const int fsub = (wv & 1) * 32;
        const int tsub = (wv >> 1) * 64;

        float hs[8];
        #pragma unroll
        for (int i = 0; i < 8; ++i) hs[i] = 0.f;

        for (int tb = 0; tb * BT2 < cnt; ++tb) {
            floatx4 acc[2][4];
            #pragma unroll
            for (int a = 0; a < 2; ++a)
                #pragma unroll
                for (int b = 0; b < 4; ++b) acc[a][b] = (floatx4)0.f;

            for (int c = 0; c < 8; ++c) {        // K chunks of 64
                const int d0 = c * 64;
                __syncthreads();
                // stage W1 tile chunk: 64 f x 64 d, fp32 -> bf16
                #pragma unroll
                for (int it = 0; it < 2; ++it) {
                    int ss = it * 256 + tid;
                    int f = ss >> 3, g = ss & 7;
                    const float* src = w1 + ((size_t)(e * FDIM + f0 + f)) * DIM + d0 + g * 8;
                    float4 a = ((const float4*)src)[0];
                    float4 b = ((const float4*)src)[1];
                    bf16x8 v;
                    v[0] = (__bf16)a.x; v[1] = (__bf16)a.y; v[2] = (__bf16)a.z; v[3] = (__bf16)a.w;
                    v[4] = (__bf16)b.x; v[5] = (__bf16)b.y; v[6] = (__bf16)b.z; v[7] = (__bf16)b.w;
                    *(bf16x8*)(w1s + ((size_t)g * 65 + f) * 8) = v;
                }
                // stage X chunk: 128 t x 64 d
                {
                    const int kg = tid & 7;
                    const int r0 = tid >> 3;
                    #pragma unroll
                    for (int it = 0; it < 4; ++it) {
                        int t = it * 32 + r0;
                        int r = tb * BT2 + t;
                        const __bf16* src = (r < cnt)
                            ? (Xg + ((size_t)(e * CAP + r)) * DIM + d0 + kg * 8)
                            : zp;
                        uint4 d = *(const uint4*)src;
                        *(uint4*)(xs + ((size_t)kg * 129 + t) * 8) = d;
                    }
                }
                __syncthreads();
                // 2 K-steps of 32 per chunk
                #pragma unroll
                for (int ks = 0; ks < 2; ++ks) {
                    const int kg = ks * 4 + q;
                    bf16x8 af0 = *(const bf16x8*)(w1s + (kg * 65 + fsub + l15) * 8);
                    bf16x8 af1 = *(const bf16x8*)(w1s + (kg * 65 + fsub + 16 + l15) * 8);
                    #pragma unroll
                    for (int tt = 0; tt < 4; ++tt) {
                        bf16x8 bfr = *(const bf16x8*)(xs + (kg * 129 + tsub + tt * 16 + l15) * 8);
                        acc[0][tt] = __builtin_amdgcn_mfma_f32_16x16x32_bf16(af0, bfr, acc[0][tt], 0, 0, 0);
                        acc[1][tt] = __builtin_amdgcn_mfma_f32_16x16x32_bf16(af1, bfr, acc[1][tt], 0, 0, 0);
                    }
                }
            }

            // silu then column-sum into hs (additive across tb)
            #pragma unroll
            for (int fa = 0; fa < 2; ++fa)
                #pragma unroll
                for (int tt = 0; tt < 4; ++tt)
                    #pragma unroll
                    for (int r = 0; r < 4; ++r) {
                        float v = acc[fa][tt][r];
                        hs[fa * 4 + r] += v / (1.f + __expf(-v));
                    }
        }

        // reduce over the 16 token-columns per quad
        #pragma unroll
        for (int i = 0; i < 8; ++i) {
            float v = hs[i];
            v += __shfl_xor(v, 1);
            v += __shfl_xor(v, 2);
            v += __shfl_xor(v, 4);
            v += __shfl_xor(v, 8);
            hs[i] = v;
        }
        if (l15 == 0) {
            #pragma unroll
            for (int fa = 0; fa < 2; ++fa)
                #pragma unroll
                for (int r = 0; r < 4; ++r) {
                    int row = fsub + fa * 16 + q * 4 + r;
                    hred[row][wv >> 1] = hs[fa * 4 + r];
                }
        }
        __syncthreads();
        if (tid < 64)    // (e,f0) block-exclusive -> plain store, no atomics
            hmean[(size_t)e * FDIM + f0 + tid] =
                (hred[tid][0] + hred[tid][1]) * inv;
    }
    grid_bar(bar, 2 * NBLK);

    // ---------------- P3: ymean (16 d per block) -----------------------------
    {
        float* hl = (float*)smem;            // 8 KB
        const int e  = bid >> 5;             // 0..15
        const int d0 = (bid & 31) * 16;
        {
            const float4* hg = (const float4*)(hmean + (size_t)e * FDIM);
            float4* hl4 = (float4*)hl;
            hl4[tid]       = hg[tid];
            hl4[256 + tid] = hg[256 + tid];
        }
        __syncthreads();

        const int wv = tid >> 6, lane = tid & 63;
        const float4* hl4 = (const float4*)hl;
        const int live = (counts[e * CNTS] > 0);
        #pragma unroll
        for (int j = 0; j < 4; ++j) {
            const int d = d0 + j * 4 + wv;
            const float4* wr = (const float4*)(w2 + ((size_t)e * DIM + d) * FDIM);
            float acc = 0.f;
            #pragma unroll
            for (int i = 0; i < 8; ++i) {
                float4 a = wr[i * 64 + lane];
                float4 h = hl4[i * 64 + lane];
                acc += a.x * h.x + a.y * h.y + a.z * h.z + a.w * h.w;
            }
            #pragma unroll
            for (int m = 1; m < 64; m <<= 1) acc += __shfl_xor(acc, m);
            if (lane == 0)
                ymean[e * DIM + d] = live ? acc : 0.f;
        }
    }
    grid_bar(bar, 3 * NBLK);

    // ---------------- P4: combine -------------------------------------------
    #pragma unroll
    for (int it = 0; it < 2; ++it) {
        const int idx = bid * 512 + it * 256 + tid;   // float4 index
        const int t = idx >> 7;
        const int c = idx & 127;
        const int i0 = top_idx[t * 2], i1 = top_idx[t * 2 + 1];
        const float w0 = routw[t * 2], w1v = routw[t * 2 + 1];
        float4 a = ((const float4*)(ymean + (size_t)i0 * DIM))[c];
        float4 b = ((const float4*)(ymean + (size_t)i1 * DIM))[c];
        float4 o;
        o.x = w0 * a.x + w1v * b.x;
        o.y = w0 * a.y + w1v * b.y;
        o.z = w0 * a.z + w1v * b.z;
        o.w = w0 * a.w + w1v * b.w;
        ((float4*)out)[idx] = o;
    }
}

extern "C" void kernel_launch(void* const* d_in, const int* in_sizes, int n_in,
                              void* d_out, int out_size, void* d_ws, size_t ws_size,
                              hipStream_t stream)
{
    (void)in_sizes; (void)n_in; (void)out_size; (void)ws_size;
    const float* x  = (const float*)d_in[0];   // [4,512,512]
    const float* gw = (const float*)d_in[1];   // [16,512]
    const float* w1 = (const float*)d_in[2];   // [16,2048,512]
    const float* w2 = (const float*)d_in[3];   // [16,512,2048]
    float* out = (float*)d_out;

    char* ws = (char*)d_ws;
    int*    counts  = (int*)   (ws + WS_COUNTS);
    int*    bar     = (int*)   (ws + WS_BAR);
    const __bf16* zp = (const __bf16*)(ws + WS_ZEROPAGE);
    int*    top_idx = (int*)   (ws + WS_TOPIDX);
    float*  routw   = (float*) (ws + WS_ROUTW);
    float*  hmean   = (float*) (ws + WS_HMEAN);
    float*  ymean   = (float*) (ws + WS_YMEAN);
    __bf16* Xg      = (__bf16*)(ws + WS_XG);

    hipMemsetAsync(d_ws, 0, WS_ZERO_BYTES, stream);   // counts + bar + zero page

    fused_moe<<<dim3(NBLK), dim3(256), 0, stream>>>(
        x, gw, w1, w2, counts, bar, top_idx, routw, Xg, zp, hmean, ymean, out);
}